// Round 1
// baseline (453.748 us; speedup 1.0000x reference)
//
#include <hip/hip_runtime.h>
#include <math.h>

#define HW 16384
#define C_DIM 256
#define V_DIM 6

// ---------------------------------------------------------------------------
// K1: M = Wq^T @ Wk.  M[i][j] = sum_o Wq[o][i] * Wk[o][j].  256x256 output.
// One block per row i, one thread per column j. Tiny (16.7 MFLOP).
// ---------------------------------------------------------------------------
__global__ void compute_M_kernel(const float* __restrict__ Wq,
                                 const float* __restrict__ Wk,
                                 float* __restrict__ M) {
    const int i = blockIdx.x;
    const int j = threadIdx.x;
    float acc = 0.f;
    for (int o = 0; o < C_DIM; ++o) {
        acc = fmaf(Wq[o * C_DIM + i], Wk[o * C_DIM + j], acc);
    }
    M[i * C_DIM + j] = acc;
}

// ---------------------------------------------------------------------------
// K2: scores.  score[v][p] = q[v,:,p]^T M k[v,:,p]
// Grid: 6 views x 128 pixel-tiles (PT=128). Block 256 threads:
//   p  = tid & 127  (pixel within tile)
//   ig = tid >> 7   (i-half: rows ig*128 .. ig*128+127)
// Loop (it x jt) 64x64 tiles of M staged in LDS (both groups' rows).
// k cached in 64 registers per (it,jt); M reads are wave-uniform -> LDS
// broadcast (free); q streamed from global (coalesced).
// Bilinear identity lets us accumulate q_i * (partial_j M_ij k_j) per tile.
// ---------------------------------------------------------------------------
__global__ __launch_bounds__(256) void score_kernel(
        const float* __restrict__ q, const float* __restrict__ k,
        const float* __restrict__ M, float* __restrict__ score) {
    const int pt = blockIdx.x & 127;
    const int v  = blockIdx.x >> 7;
    const int p  = threadIdx.x & 127;
    const int ig = threadIdx.x >> 7;      // 0 or 1
    const int gp = pt * 128 + p;

    const float* qv = q + (size_t)v * C_DIM * HW + gp;
    const float* kv = k + (size_t)v * C_DIM * HW + gp;

    __shared__ __align__(16) float M_lds[2][64 * 64];   // 32 KB
    __shared__ float s_lds[2][128];

    float sacc = 0.f;

    for (int it = 0; it < 2; ++it) {
        for (int jt = 0; jt < 4; ++jt) {
            __syncthreads();
            // Cooperative load: group g needs M rows [g*128+it*64 .. +64),
            // cols [jt*64 .. +64). 8192 floats, 32 per thread, coalesced.
            for (int e = 0; e < 32; ++e) {
                int idx = threadIdx.x + 256 * e;     // 0..8191
                int g   = idx >> 12;                 // 4096 entries per group
                int rc  = idx & 4095;
                int r   = rc >> 6;
                int c   = rc & 63;
                M_lds[g][rc] = M[(g * 128 + it * 64 + r) * C_DIM + jt * 64 + c];
            }
            __syncthreads();

            // k fragment for this j-tile into registers (fully unrolled ->
            // static indexing, stays in VGPRs).
            float kreg[64];
            #pragma unroll
            for (int jj = 0; jj < 64; ++jj) {
                kreg[jj] = kv[(size_t)(jt * 64 + jj) * HW];
            }

            const int ibase = ig * 128 + it * 64;
            const float* Mg = M_lds[ig];
            for (int ii = 0; ii < 64; ++ii) {
                const float4* Mrow = (const float4*)(Mg + ii * 64);
                float t0 = 0.f, t1 = 0.f, t2 = 0.f, t3 = 0.f;
                #pragma unroll
                for (int j4 = 0; j4 < 16; ++j4) {
                    float4 m4 = Mrow[j4];            // wave-uniform broadcast
                    t0 = fmaf(m4.x, kreg[4 * j4 + 0], t0);
                    t1 = fmaf(m4.y, kreg[4 * j4 + 1], t1);
                    t2 = fmaf(m4.z, kreg[4 * j4 + 2], t2);
                    t3 = fmaf(m4.w, kreg[4 * j4 + 3], t3);
                }
                float t = (t0 + t1) + (t2 + t3);
                sacc = fmaf(qv[(size_t)(ibase + ii) * HW], t, sacc);
            }
        }
    }

    // reduce the two i-halves
    s_lds[ig][p] = sacc;
    __syncthreads();
    if (threadIdx.x < 128) {
        score[v * HW + pt * 128 + threadIdx.x] =
            s_lds[0][threadIdx.x] + s_lds[1][threadIdx.x];
    }
}

// ---------------------------------------------------------------------------
// K3: softmax over views + out = Wv @ (sum_v w_v * v_v), fused (v read once).
// Grid: 512 blocks, PT=32 pixels each. Block 256 threads:
//   p  = tid & 31   (pixel)
//   og = tid >> 5   (8 groups x 32 output channels; acc[32] per thread)
// Per 16-wide c-tile: stage Wv[256][16] in LDS, build X[p][c] = vbar on the
// fly from v and softmax weights, then rank-16 update of acc.
// ---------------------------------------------------------------------------
__global__ __launch_bounds__(256) void out_kernel(
        const float* __restrict__ vin, const float* __restrict__ Wv,
        const float* __restrict__ score, float* __restrict__ out) {
    const int p0 = blockIdx.x * 32;
    const int p  = threadIdx.x & 31;
    const int og = threadIdx.x >> 5;     // 0..7

    __shared__ float w_lds[V_DIM][32];
    __shared__ __align__(16) float Wv_lds[256 * 16];   // 16 KB  [o][cw]
    __shared__ __align__(16) float X_lds[32][20];      // [p][cw], pad 16->20

    // softmax over the 6 views for this block's 32 pixels
    if (threadIdx.x < 32) {
        int pp = p0 + threadIdx.x;
        float s[V_DIM];
        float mx = -1e30f;
        #pragma unroll
        for (int vv = 0; vv < V_DIM; ++vv) {
            s[vv] = score[vv * HW + pp];
            mx = fmaxf(mx, s[vv]);
        }
        float sum = 0.f;
        #pragma unroll
        for (int vv = 0; vv < V_DIM; ++vv) {
            s[vv] = __expf(s[vv] - mx);
            sum += s[vv];
        }
        float inv = 1.0f / sum;
        #pragma unroll
        for (int vv = 0; vv < V_DIM; ++vv) {
            w_lds[vv][threadIdx.x] = s[vv] * inv;
        }
    }

    float acc[32];
    #pragma unroll
    for (int oi = 0; oi < 32; ++oi) acc[oi] = 0.f;

    for (int ct = 0; ct < 16; ++ct) {            // c-tiles of width 16
        __syncthreads();                         // also orders w_lds at ct=0
        // stage Wv[o][ct*16 + cw], 4096 floats, 16 per thread
        for (int e = 0; e < 16; ++e) {
            int idx = threadIdx.x + 256 * e;
            int o   = idx >> 4;
            int cw  = idx & 15;
            Wv_lds[idx] = Wv[o * C_DIM + ct * 16 + cw];
        }
        // build X[p][cw] = sum_v w_v * v[v, ct*16+cw, p]  (2 entries/thread)
        #pragma unroll
        for (int e = 0; e < 2; ++e) {
            int cw = og * 2 + e;                 // 0..15
            float xv = 0.f;
            #pragma unroll
            for (int vv = 0; vv < V_DIM; ++vv) {
                xv = fmaf(w_lds[vv][p],
                          vin[(size_t)(vv * C_DIM + ct * 16 + cw) * HW + p0 + p],
                          xv);
            }
            X_lds[p][cw] = xv;
        }
        __syncthreads();

        // acc[oi] += Wv[o][c-tile] . X[p][c-tile]
        const float4* X4 = (const float4*)(&X_lds[p][0]);
        for (int c4 = 0; c4 < 4; ++c4) {
            float4 xr = X4[c4];
            #pragma unroll
            for (int oi = 0; oi < 32; ++oi) {
                const float4* wv4p =
                    (const float4*)(Wv_lds + (og * 32 + oi) * 16) + c4;
                float4 wv = *wv4p;               // half-wave-uniform broadcast
                acc[oi] = fmaf(wv.x, xr.x, acc[oi]);
                acc[oi] = fmaf(wv.y, xr.y, acc[oi]);
                acc[oi] = fmaf(wv.z, xr.z, acc[oi]);
                acc[oi] = fmaf(wv.w, xr.w, acc[oi]);
            }
        }
    }

    // write out[o][p0+p], coalesced
    #pragma unroll
    for (int oi = 0; oi < 32; ++oi) {
        out[(size_t)(og * 32 + oi) * HW + p0 + p] = acc[oi];
    }
}

// ---------------------------------------------------------------------------
extern "C" void kernel_launch(void* const* d_in, const int* in_sizes, int n_in,
                              void* d_out, int out_size, void* d_ws, size_t ws_size,
                              hipStream_t stream) {
    const float* q  = (const float*)d_in[0];
    const float* k  = (const float*)d_in[1];
    const float* v  = (const float*)d_in[2];
    const float* Wq = (const float*)d_in[3];
    const float* Wk = (const float*)d_in[4];
    const float* Wv = (const float*)d_in[5];
    float* out = (float*)d_out;

    float* M     = (float*)d_ws;                 // 256*256 floats = 256 KB
    float* score = M + C_DIM * C_DIM;            // 6*16384 floats = 384 KB

    compute_M_kernel<<<C_DIM, C_DIM, 0, stream>>>(Wq, Wk, M);
    score_kernel<<<V_DIM * 128, 256, 0, stream>>>(q, k, M, score);
    out_kernel<<<HW / 32, 256, 0, stream>>>(v, Wv, score, out);
}

// Round 2
// 189.176 us; speedup vs baseline: 2.3986x; 2.3986x over previous
//
#include <hip/hip_runtime.h>
#include <math.h>

#define HW 16384
#define C_DIM 256
#define V_DIM 6

typedef short bf16x8 __attribute__((ext_vector_type(8)));
typedef float f32x4 __attribute__((ext_vector_type(4)));

__device__ __forceinline__ unsigned short f2bf(float x) {
    unsigned u = __float_as_uint(x);
    u += 0x7FFFu + ((u >> 16) & 1u);          // round-to-nearest-even
    return (unsigned short)(u >> 16);
}
__device__ __forceinline__ float bf2f(unsigned short h) {
    return __uint_as_float(((unsigned)h) << 16);
}

// ---------------------------------------------------------------------------
// K1: M = Wq^T @ Wk, emitted directly as split-bf16 (Mh + Ml ~= M to 2^-17).
// ---------------------------------------------------------------------------
__global__ void compute_M_kernel(const float* __restrict__ Wq,
                                 const float* __restrict__ Wk,
                                 unsigned short* __restrict__ Mh,
                                 unsigned short* __restrict__ Ml) {
    const int i = blockIdx.x;
    const int j = threadIdx.x;
    float acc = 0.f;
    for (int o = 0; o < C_DIM; ++o)
        acc = fmaf(Wq[o * C_DIM + i], Wk[o * C_DIM + j], acc);
    unsigned short h = f2bf(acc);
    Mh[i * C_DIM + j] = h;
    Ml[i * C_DIM + j] = f2bf(acc - bf2f(h));
}

// ---------------------------------------------------------------------------
// K2: score[v][p] = q[v,:,p]^T M k[v,:,p] via MFMA split-bf16.
// Block: 256 thr = 4 waves, p-tile 64 pixels, wave w owns i-rows [64w,64w+64).
// K-loop j in steps of BK=32: stage M[256][32] (hi/lo, pre-split) and
// K[64p][32j] (hi/lo, split on the fly) into padded LDS (row=40 ushorts,
// word-stride 20 -> banks spread), then 4x4 16x16x32 MFMAs x3 split terms.
// Epilogue: fp32 dot with q over the in-register T tile + shuffle/LDS reduce.
// ---------------------------------------------------------------------------
#define PT 64
#define BK 32
#define MROW 40

__global__ __launch_bounds__(256) void score_kernel(
        const float* __restrict__ q, const float* __restrict__ k,
        const unsigned short* __restrict__ Mh,
        const unsigned short* __restrict__ Ml,
        float* __restrict__ score) {
    const int tid  = threadIdx.x;
    const int lane = tid & 63;
    const int w    = tid >> 6;
    const int pt   = blockIdx.x & 255;
    const int v    = blockIdx.x >> 8;
    const int gp0  = pt * PT;

    __shared__ __align__(16) unsigned short Mh_s[C_DIM * MROW];  // 20 KB
    __shared__ __align__(16) unsigned short Ml_s[C_DIM * MROW];  // 20 KB
    __shared__ __align__(16) unsigned short Kh_s[PT * MROW];     // 5 KB
    __shared__ __align__(16) unsigned short Kl_s[PT * MROW];     // 5 KB
    __shared__ float s_red[4][PT];                               // 1 KB

    const float* kv = k + (size_t)v * C_DIM * HW + gp0;
    const float* qv = q + (size_t)v * C_DIM * HW + gp0;

    f32x4 acc[4][4];
    #pragma unroll
    for (int a = 0; a < 4; ++a)
        #pragma unroll
        for (int b = 0; b < 4; ++b)
            acc[a][b] = (f32x4){0.f, 0.f, 0.f, 0.f};

    const int ibase = w * 64;
    const int l15 = lane & 15;
    const int l4  = lane >> 4;

    for (int ks = 0; ks < C_DIM / BK; ++ks) {
        const int j0 = ks * BK;
        // --- stage M tile (bf16 copy, 16B loads, padded-row LDS writes) ---
        #pragma unroll
        for (int e = 0; e < 4; ++e) {
            int cidx = tid + 256 * e;           // 0..1023 chunks of 8
            int i  = cidx >> 2;
            int jb = cidx & 3;
            uint4 mh = *(const uint4*)(Mh + i * C_DIM + j0 + jb * 8);
            uint4 ml = *(const uint4*)(Ml + i * C_DIM + j0 + jb * 8);
            *(uint4*)&Mh_s[i * MROW + jb * 8] = mh;
            *(uint4*)&Ml_s[i * MROW + jb * 8] = ml;
        }
        // --- stage K tile with fp32 -> (hi,lo) split ---
        #pragma unroll
        for (int e = 0; e < 4; ++e) {
            int pidx = tid + 256 * e;           // 0..1023 pairs
            int p  = pidx & 63;
            int jp = pidx >> 6;                 // 0..15
            const float* kp = kv + (size_t)(j0 + jp * 2) * HW + p;
            float x0 = kp[0];
            float x1 = kp[HW];
            unsigned short h0 = f2bf(x0), h1 = f2bf(x1);
            unsigned short lo0 = f2bf(x0 - bf2f(h0));
            unsigned short lo1 = f2bf(x1 - bf2f(h1));
            *(unsigned*)&Kh_s[p * MROW + jp * 2] = (unsigned)h0 | ((unsigned)h1 << 16);
            *(unsigned*)&Kl_s[p * MROW + jp * 2] = (unsigned)lo0 | ((unsigned)lo1 << 16);
        }
        __syncthreads();

        // --- fragments: A row = lane&15, k = 8*(lane>>4)+e (j-contiguous) ---
        bf16x8 Ah[4], Al[4], Bh[4], Bl[4];
        #pragma unroll
        for (int it = 0; it < 4; ++it) {
            int ai = ibase + it * 16 + l15;
            Ah[it] = *(const bf16x8*)&Mh_s[ai * MROW + l4 * 8];
            Al[it] = *(const bf16x8*)&Ml_s[ai * MROW + l4 * 8];
        }
        #pragma unroll
        for (int jt = 0; jt < 4; ++jt) {
            int bp = jt * 16 + l15;
            Bh[jt] = *(const bf16x8*)&Kh_s[bp * MROW + l4 * 8];
            Bl[jt] = *(const bf16x8*)&Kl_s[bp * MROW + l4 * 8];
        }
        #pragma unroll
        for (int it = 0; it < 4; ++it)
            #pragma unroll
            for (int jt = 0; jt < 4; ++jt) {
                acc[it][jt] = __builtin_amdgcn_mfma_f32_16x16x32_bf16(
                                  Ah[it], Bh[jt], acc[it][jt], 0, 0, 0);
                acc[it][jt] = __builtin_amdgcn_mfma_f32_16x16x32_bf16(
                                  Ah[it], Bl[jt], acc[it][jt], 0, 0, 0);
                acc[it][jt] = __builtin_amdgcn_mfma_f32_16x16x32_bf16(
                                  Al[it], Bh[jt], acc[it][jt], 0, 0, 0);
            }
        __syncthreads();
    }

    // --- epilogue: sp[p] = sum_i q[i,p] * T[i,p] ---
    // D layout: row i = (lane>>4)*4 + r (+16*it), col p = lane&15 (+16*jt)
    float sp[4];
    #pragma unroll
    for (int jt = 0; jt < 4; ++jt) sp[jt] = 0.f;
    #pragma unroll
    for (int jt = 0; jt < 4; ++jt) {
        #pragma unroll
        for (int it = 0; it < 4; ++it) {
            int irow = ibase + it * 16 + l4 * 4;
            const float* qp = qv + (size_t)irow * HW + jt * 16 + l15;
            #pragma unroll
            for (int r = 0; r < 4; ++r)
                sp[jt] = fmaf(qp[(size_t)r * HW], acc[it][jt][r], sp[jt]);
        }
        sp[jt] += __shfl_xor(sp[jt], 16, 64);
        sp[jt] += __shfl_xor(sp[jt], 32, 64);
    }
    if (lane < 16) {
        #pragma unroll
        for (int jt = 0; jt < 4; ++jt)
            s_red[w][jt * 16 + lane] = sp[jt];
    }
    __syncthreads();
    if (tid < PT) {
        score[v * HW + gp0 + tid] =
            s_red[0][tid] + s_red[1][tid] + s_red[2][tid] + s_red[3][tid];
    }
}

// ---------------------------------------------------------------------------
// K3: softmax over views + out = Wv @ (sum_v w_v * v_v)   (unchanged)
// ---------------------------------------------------------------------------
__global__ __launch_bounds__(256) void out_kernel(
        const float* __restrict__ vin, const float* __restrict__ Wv,
        const float* __restrict__ score, float* __restrict__ out) {
    const int p0 = blockIdx.x * 32;
    const int p  = threadIdx.x & 31;
    const int og = threadIdx.x >> 5;

    __shared__ float w_lds[V_DIM][32];
    __shared__ __align__(16) float Wv_lds[256 * 16];
    __shared__ __align__(16) float X_lds[32][20];

    if (threadIdx.x < 32) {
        int pp = p0 + threadIdx.x;
        float s[V_DIM];
        float mx = -1e30f;
        #pragma unroll
        for (int vv = 0; vv < V_DIM; ++vv) {
            s[vv] = score[vv * HW + pp];
            mx = fmaxf(mx, s[vv]);
        }
        float sum = 0.f;
        #pragma unroll
        for (int vv = 0; vv < V_DIM; ++vv) {
            s[vv] = __expf(s[vv] - mx);
            sum += s[vv];
        }
        float inv = 1.0f / sum;
        #pragma unroll
        for (int vv = 0; vv < V_DIM; ++vv)
            w_lds[vv][threadIdx.x] = s[vv] * inv;
    }

    float acc[32];
    #pragma unroll
    for (int oi = 0; oi < 32; ++oi) acc[oi] = 0.f;

    for (int ct = 0; ct < 16; ++ct) {
        __syncthreads();
        for (int e = 0; e < 16; ++e) {
            int idx = threadIdx.x + 256 * e;
            int o   = idx >> 4;
            int cw  = idx & 15;
            Wv_lds[idx] = Wv[o * C_DIM + ct * 16 + cw];
        }
        #pragma unroll
        for (int e = 0; e < 2; ++e) {
            int cw = og * 2 + e;
            float xv = 0.f;
            #pragma unroll
            for (int vv = 0; vv < V_DIM; ++vv) {
                xv = fmaf(w_lds[vv][p],
                          vin[(size_t)(vv * C_DIM + ct * 16 + cw) * HW + p0 + p],
                          xv);
            }
            X_lds[p][cw] = xv;
        }
        __syncthreads();

        const float4* X4 = (const float4*)(&X_lds[p][0]);
        for (int c4 = 0; c4 < 4; ++c4) {
            float4 xr = X4[c4];
            #pragma unroll
            for (int oi = 0; oi < 32; ++oi) {
                const float4* wv4p =
                    (const float4*)(Wv_lds + (og * 32 + oi) * 16) + c4;
                float4 wv = *wv4p;
                acc[oi] = fmaf(wv.x, xr.x, acc[oi]);
                acc[oi] = fmaf(wv.y, xr.y, acc[oi]);
                acc[oi] = fmaf(wv.z, xr.z, acc[oi]);
                acc[oi] = fmaf(wv.w, xr.w, acc[oi]);
            }
        }
    }

    #pragma unroll
    for (int oi = 0; oi < 32; ++oi)
        out[(size_t)(og * 32 + oi) * HW + p0 + p] = acc[oi];
}

// ---------------------------------------------------------------------------
extern "C" void kernel_launch(void* const* d_in, const int* in_sizes, int n_in,
                              void* d_out, int out_size, void* d_ws, size_t ws_size,
                              hipStream_t stream) {
    const float* q  = (const float*)d_in[0];
    const float* k  = (const float*)d_in[1];
    const float* v  = (const float*)d_in[2];
    const float* Wq = (const float*)d_in[3];
    const float* Wk = (const float*)d_in[4];
    const float* Wv = (const float*)d_in[5];
    float* out = (float*)d_out;

    unsigned short* Mh = (unsigned short*)d_ws;          // 128 KB
    unsigned short* Ml = Mh + C_DIM * C_DIM;             // 128 KB
    float* score = (float*)(Ml + C_DIM * C_DIM);         // 384 KB

    compute_M_kernel<<<C_DIM, C_DIM, 0, stream>>>(Wq, Wk, Mh, Ml);
    score_kernel<<<V_DIM * 256, 256, 0, stream>>>(q, k, Mh, Ml, score);
    out_kernel<<<HW / 32, 256, 0, stream>>>(v, Wv, score, out);
}

// Round 3
// 123.407 us; speedup vs baseline: 3.6769x; 1.5329x over previous
//
#include <hip/hip_runtime.h>
#include <math.h>

#define HW 16384
#define C_DIM 256
#define V_DIM 6

typedef short bf16x8 __attribute__((ext_vector_type(8)));
typedef float f32x4 __attribute__((ext_vector_type(4)));

__device__ __forceinline__ unsigned short f2bf(float x) {
    unsigned u = __float_as_uint(x);
    u += 0x7FFFu + ((u >> 16) & 1u);          // round-to-nearest-even
    return (unsigned short)(u >> 16);
}
__device__ __forceinline__ float bf2f(unsigned short h) {
    return __uint_as_float(((unsigned)h) << 16);
}

// ---------------------------------------------------------------------------
// K1: M = Wq^T @ Wk, emitted directly as split-bf16 (Mh + Ml ~= M to 2^-17).
// ---------------------------------------------------------------------------
__global__ void compute_M_kernel(const float* __restrict__ Wq,
                                 const float* __restrict__ Wk,
                                 unsigned short* __restrict__ Mh,
                                 unsigned short* __restrict__ Ml) {
    const int i = blockIdx.x;
    const int j = threadIdx.x;
    float acc = 0.f;
    for (int o = 0; o < C_DIM; ++o)
        acc = fmaf(Wq[o * C_DIM + i], Wk[o * C_DIM + j], acc);
    unsigned short h = f2bf(acc);
    Mh[i * C_DIM + j] = h;
    Ml[i * C_DIM + j] = f2bf(acc - bf2f(h));
}

// ---------------------------------------------------------------------------
// K2: score[v][p] = q[v,:,p]^T M k[v,:,p] via MFMA split-bf16.  (unchanged)
// ---------------------------------------------------------------------------
#define PT 64
#define BK 32
#define MROW 40

__global__ __launch_bounds__(256) void score_kernel(
        const float* __restrict__ q, const float* __restrict__ k,
        const unsigned short* __restrict__ Mh,
        const unsigned short* __restrict__ Ml,
        float* __restrict__ score) {
    const int tid  = threadIdx.x;
    const int lane = tid & 63;
    const int w    = tid >> 6;
    const int pt   = blockIdx.x & 255;
    const int v    = blockIdx.x >> 8;
    const int gp0  = pt * PT;

    __shared__ __align__(16) unsigned short Mh_s[C_DIM * MROW];
    __shared__ __align__(16) unsigned short Ml_s[C_DIM * MROW];
    __shared__ __align__(16) unsigned short Kh_s[PT * MROW];
    __shared__ __align__(16) unsigned short Kl_s[PT * MROW];
    __shared__ float s_red[4][PT];

    const float* kv = k + (size_t)v * C_DIM * HW + gp0;
    const float* qv = q + (size_t)v * C_DIM * HW + gp0;

    f32x4 acc[4][4];
    #pragma unroll
    for (int a = 0; a < 4; ++a)
        #pragma unroll
        for (int b = 0; b < 4; ++b)
            acc[a][b] = (f32x4){0.f, 0.f, 0.f, 0.f};

    const int ibase = w * 64;
    const int l15 = lane & 15;
    const int l4  = lane >> 4;

    for (int ks = 0; ks < C_DIM / BK; ++ks) {
        const int j0 = ks * BK;
        #pragma unroll
        for (int e = 0; e < 4; ++e) {
            int cidx = tid + 256 * e;
            int i  = cidx >> 2;
            int jb = cidx & 3;
            uint4 mh = *(const uint4*)(Mh + i * C_DIM + j0 + jb * 8);
            uint4 ml = *(const uint4*)(Ml + i * C_DIM + j0 + jb * 8);
            *(uint4*)&Mh_s[i * MROW + jb * 8] = mh;
            *(uint4*)&Ml_s[i * MROW + jb * 8] = ml;
        }
        #pragma unroll
        for (int e = 0; e < 4; ++e) {
            int pidx = tid + 256 * e;
            int p  = pidx & 63;
            int jp = pidx >> 6;
            const float* kp = kv + (size_t)(j0 + jp * 2) * HW + p;
            float x0 = kp[0];
            float x1 = kp[HW];
            unsigned short h0 = f2bf(x0), h1 = f2bf(x1);
            unsigned short lo0 = f2bf(x0 - bf2f(h0));
            unsigned short lo1 = f2bf(x1 - bf2f(h1));
            *(unsigned*)&Kh_s[p * MROW + jp * 2] = (unsigned)h0 | ((unsigned)h1 << 16);
            *(unsigned*)&Kl_s[p * MROW + jp * 2] = (unsigned)lo0 | ((unsigned)lo1 << 16);
        }
        __syncthreads();

        bf16x8 Ah[4], Al[4], Bh[4], Bl[4];
        #pragma unroll
        for (int it = 0; it < 4; ++it) {
            int ai = ibase + it * 16 + l15;
            Ah[it] = *(const bf16x8*)&Mh_s[ai * MROW + l4 * 8];
            Al[it] = *(const bf16x8*)&Ml_s[ai * MROW + l4 * 8];
        }
        #pragma unroll
        for (int jt = 0; jt < 4; ++jt) {
            int bp = jt * 16 + l15;
            Bh[jt] = *(const bf16x8*)&Kh_s[bp * MROW + l4 * 8];
            Bl[jt] = *(const bf16x8*)&Kl_s[bp * MROW + l4 * 8];
        }
        #pragma unroll
        for (int it = 0; it < 4; ++it)
            #pragma unroll
            for (int jt = 0; jt < 4; ++jt) {
                acc[it][jt] = __builtin_amdgcn_mfma_f32_16x16x32_bf16(
                                  Ah[it], Bh[jt], acc[it][jt], 0, 0, 0);
                acc[it][jt] = __builtin_amdgcn_mfma_f32_16x16x32_bf16(
                                  Ah[it], Bl[jt], acc[it][jt], 0, 0, 0);
                acc[it][jt] = __builtin_amdgcn_mfma_f32_16x16x32_bf16(
                                  Al[it], Bh[jt], acc[it][jt], 0, 0, 0);
            }
        __syncthreads();
    }

    float sp[4];
    #pragma unroll
    for (int jt = 0; jt < 4; ++jt) sp[jt] = 0.f;
    #pragma unroll
    for (int jt = 0; jt < 4; ++jt) {
        #pragma unroll
        for (int it = 0; it < 4; ++it) {
            int irow = ibase + it * 16 + l4 * 4;
            const float* qp = qv + (size_t)irow * HW + jt * 16 + l15;
            #pragma unroll
            for (int r = 0; r < 4; ++r)
                sp[jt] = fmaf(qp[(size_t)r * HW], acc[it][jt][r], sp[jt]);
        }
        sp[jt] += __shfl_xor(sp[jt], 16, 64);
        sp[jt] += __shfl_xor(sp[jt], 32, 64);
    }
    if (lane < 16) {
        #pragma unroll
        for (int jt = 0; jt < 4; ++jt)
            s_red[w][jt * 16 + lane] = sp[jt];
    }
    __syncthreads();
    if (tid < PT) {
        score[v * HW + gp0 + tid] =
            s_red[0][tid] + s_red[1][tid] + s_red[2][tid] + s_red[3][tid];
    }
}

// ---------------------------------------------------------------------------
// K3: in-place softmax over views: score[v][p] -> w[v][p].
// ---------------------------------------------------------------------------
__global__ __launch_bounds__(256) void softmax_w_kernel(float* __restrict__ score) {
    const int p = blockIdx.x * 256 + threadIdx.x;
    float s[V_DIM];
    float mx = -1e30f;
    #pragma unroll
    for (int vv = 0; vv < V_DIM; ++vv) {
        s[vv] = score[vv * HW + p];
        mx = fmaxf(mx, s[vv]);
    }
    float sum = 0.f;
    #pragma unroll
    for (int vv = 0; vv < V_DIM; ++vv) {
        s[vv] = __expf(s[vv] - mx);
        sum += s[vv];
    }
    float inv = 1.0f / sum;
    #pragma unroll
    for (int vv = 0; vv < V_DIM; ++vv)
        score[vv * HW + p] = s[vv] * inv;
}

// ---------------------------------------------------------------------------
// K4: split Wv into bf16 hi/lo, reusing the Mh/Ml workspace (score_kernel
// is done with M by the time this runs; stream order guarantees it).
// ---------------------------------------------------------------------------
__global__ void wsplit_kernel(const float* __restrict__ Wv,
                              unsigned short* __restrict__ Wvh,
                              unsigned short* __restrict__ Wvl) {
    const int i = blockIdx.x;
    const int j = threadIdx.x;
    float x = Wv[i * C_DIM + j];
    unsigned short h = f2bf(x);
    Wvh[i * C_DIM + j] = h;
    Wvl[i * C_DIM + j] = f2bf(x - bf2f(h));
}

// ---------------------------------------------------------------------------
// K5: out[o][p] = sum_c Wv[o][c] * vbar[c][p],  vbar[c][p] = sum_v w[v][p]*v[v][c][p]
// Split-bf16 MFMA GEMM, vbar built on the fly (v read exactly once).
// Grid: 256 blocks (64-pixel tiles). Block: 512 thr = 8 waves; wave w owns
// o-rows [32w, 32w+32). K-loop c in steps of 32, padded LDS rows (MROW=40).
// ---------------------------------------------------------------------------
__global__ __launch_bounds__(512) void out_gemm_kernel(
        const float* __restrict__ vin,
        const unsigned short* __restrict__ Wvh,
        const unsigned short* __restrict__ Wvl,
        const float* __restrict__ wsm,      // softmax weights [V][HW]
        float* __restrict__ out) {
    const int tid  = threadIdx.x;
    const int lane = tid & 63;
    const int w    = tid >> 6;              // 0..7
    const int gp0  = blockIdx.x * PT;

    __shared__ __align__(16) unsigned short Wh_s[C_DIM * MROW];  // 20 KB
    __shared__ __align__(16) unsigned short Wl_s[C_DIM * MROW];  // 20 KB
    __shared__ __align__(16) unsigned short Xh_s[PT * MROW];     // 5 KB
    __shared__ __align__(16) unsigned short Xl_s[PT * MROW];     // 5 KB
    __shared__ float w_s[V_DIM][PT];

    // stage softmax weights for this pixel tile
    if (tid < V_DIM * PT) {
        int vv = tid >> 6;
        int p  = tid & 63;
        w_s[vv][p] = wsm[vv * HW + gp0 + p];
    }

    f32x4 acc[2][4];
    #pragma unroll
    for (int a = 0; a < 2; ++a)
        #pragma unroll
        for (int b = 0; b < 4; ++b)
            acc[a][b] = (f32x4){0.f, 0.f, 0.f, 0.f};

    const int obase = w * 32;
    const int l15 = lane & 15;
    const int l4  = lane >> 4;

    for (int ks = 0; ks < C_DIM / BK; ++ks) {
        const int c0 = ks * BK;
        __syncthreads();   // prev-iter frag reads done; w_s ready at ks=0
        // --- stage Wv tile [256][32] hi/lo (pre-split, 16B chunks) ---
        #pragma unroll
        for (int e = 0; e < 2; ++e) {
            int cidx = tid + 512 * e;        // 0..1023
            int i  = cidx >> 2;
            int jb = cidx & 3;
            uint4 wh = *(const uint4*)(Wvh + i * C_DIM + c0 + jb * 8);
            uint4 wl = *(const uint4*)(Wvl + i * C_DIM + c0 + jb * 8);
            *(uint4*)&Wh_s[i * MROW + jb * 8] = wh;
            *(uint4*)&Wl_s[i * MROW + jb * 8] = wl;
        }
        // --- build X tile [64p][32c]: vbar split on the fly ---
        #pragma unroll
        for (int e = 0; e < 2; ++e) {
            int pidx = tid + 512 * e;        // 0..1023 pairs
            int p  = pidx & 63;
            int jp = pidx >> 6;              // 0..15 (c-pair)
            const float* vp = vin + (size_t)(c0 + jp * 2) * HW + gp0 + p;
            float x0 = 0.f, x1 = 0.f;
            #pragma unroll
            for (int vv = 0; vv < V_DIM; ++vv) {
                float wv = w_s[vv][p];
                const float* vvp = vp + (size_t)vv * C_DIM * HW;
                x0 = fmaf(wv, vvp[0], x0);
                x1 = fmaf(wv, vvp[HW], x1);
            }
            unsigned short h0 = f2bf(x0), h1 = f2bf(x1);
            unsigned short lo0 = f2bf(x0 - bf2f(h0));
            unsigned short lo1 = f2bf(x1 - bf2f(h1));
            *(unsigned*)&Xh_s[p * MROW + jp * 2] = (unsigned)h0 | ((unsigned)h1 << 16);
            *(unsigned*)&Xl_s[p * MROW + jp * 2] = (unsigned)lo0 | ((unsigned)lo1 << 16);
        }
        __syncthreads();

        bf16x8 Ah[2], Al[2], Bh[4], Bl[4];
        #pragma unroll
        for (int it = 0; it < 2; ++it) {
            int ai = obase + it * 16 + l15;
            Ah[it] = *(const bf16x8*)&Wh_s[ai * MROW + l4 * 8];
            Al[it] = *(const bf16x8*)&Wl_s[ai * MROW + l4 * 8];
        }
        #pragma unroll
        for (int jt = 0; jt < 4; ++jt) {
            int bp = jt * 16 + l15;
            Bh[jt] = *(const bf16x8*)&Xh_s[bp * MROW + l4 * 8];
            Bl[jt] = *(const bf16x8*)&Xl_s[bp * MROW + l4 * 8];
        }
        #pragma unroll
        for (int it = 0; it < 2; ++it)
            #pragma unroll
            for (int jt = 0; jt < 4; ++jt) {
                acc[it][jt] = __builtin_amdgcn_mfma_f32_16x16x32_bf16(
                                  Ah[it], Bh[jt], acc[it][jt], 0, 0, 0);
                acc[it][jt] = __builtin_amdgcn_mfma_f32_16x16x32_bf16(
                                  Ah[it], Bl[jt], acc[it][jt], 0, 0, 0);
                acc[it][jt] = __builtin_amdgcn_mfma_f32_16x16x32_bf16(
                                  Al[it], Bh[jt], acc[it][jt], 0, 0, 0);
            }
    }

    // --- store D tile: o = obase + it*16 + l4*4 + r,  p = jt*16 + l15 ---
    #pragma unroll
    for (int it = 0; it < 2; ++it)
        #pragma unroll
        for (int jt = 0; jt < 4; ++jt) {
            #pragma unroll
            for (int r = 0; r < 4; ++r) {
                int o = obase + it * 16 + l4 * 4 + r;
                out[(size_t)o * HW + gp0 + jt * 16 + l15] = acc[it][jt][r];
            }
        }
}

// ---------------------------------------------------------------------------
extern "C" void kernel_launch(void* const* d_in, const int* in_sizes, int n_in,
                              void* d_out, int out_size, void* d_ws, size_t ws_size,
                              hipStream_t stream) {
    const float* q  = (const float*)d_in[0];
    const float* k  = (const float*)d_in[1];
    const float* v  = (const float*)d_in[2];
    const float* Wq = (const float*)d_in[3];
    const float* Wk = (const float*)d_in[4];
    const float* Wv = (const float*)d_in[5];
    float* out = (float*)d_out;

    unsigned short* Mh = (unsigned short*)d_ws;          // 128 KB (later: Wvh)
    unsigned short* Ml = Mh + C_DIM * C_DIM;             // 128 KB (later: Wvl)
    float* score = (float*)(Ml + C_DIM * C_DIM);         // 384 KB (later: w)

    compute_M_kernel<<<C_DIM, C_DIM, 0, stream>>>(Wq, Wk, Mh, Ml);
    score_kernel<<<V_DIM * 256, 256, 0, stream>>>(q, k, Mh, Ml, score);
    softmax_w_kernel<<<HW / 256, 256, 0, stream>>>(score);
    wsplit_kernel<<<C_DIM, C_DIM, 0, stream>>>(Wv, Mh, Ml);   // reuse M buffers
    out_gemm_kernel<<<HW / PT, 512, 0, stream>>>(v, Mh, Ml, score, out);
}